// Round 4
// baseline (507.817 us; speedup 1.0000x reference)
//
#include <hip/hip_runtime.h>
#include <math.h>

#define HIDDEN 4096
#define NEXP   128
#define TOPK   8
#define BM     32
#define BKC    64                  // K per chunk (wave does its wk-half: K=32)
#define NCHUNK (HIDDEN / BKC)      // 64
#define SS     132                 // padded stride for score rows in epilogue

typedef __attribute__((ext_vector_type(8))) short short8;  // 8 bf16 (4 VGPR)
typedef __attribute__((ext_vector_type(4))) float f32x4;   // MFMA accumulator

__device__ __forceinline__ unsigned pack2(unsigned a, unsigned b) {
  // low ushort = top16 of a, high ushort = top16 of b
  return (a >> 16) | (b & 0xFFFF0000u);
}

// Triple bf16 split: x = hi + mid + lo + O(2^-24 x). hi/mid round-half-away.
struct Split3 { uint4 h, m, l; };
__device__ __forceinline__ Split3 split8(float4 a, float4 b) {
  float x[8] = {a.x, a.y, a.z, a.w, b.x, b.y, b.z, b.w};
  unsigned h[8], m[8], l[8];
#pragma unroll
  for (int j = 0; j < 8; ++j) {
    unsigned u  = __float_as_uint(x[j]);
    unsigned hb = (u + 0x8000u) & 0xFFFF0000u;
    float rh    = x[j] - __uint_as_float(hb);
    unsigned um = __float_as_uint(rh);
    unsigned mb = (um + 0x8000u) & 0xFFFF0000u;
    float rm    = rh - __uint_as_float(mb);
    h[j] = hb; m[j] = mb; l[j] = __float_as_uint(rm);
  }
  Split3 s;
  s.h = make_uint4(pack2(h[0],h[1]), pack2(h[2],h[3]), pack2(h[4],h[5]), pack2(h[6],h[7]));
  s.m = make_uint4(pack2(m[0],m[1]), pack2(m[2],m[3]), pack2(m[4],m[5]), pack2(m[6],m[7]));
  s.l = make_uint4(pack2(l[0],l[1]), pack2(l[2],l[3]), pack2(l[4],l[5]), pack2(l[6],l[7]));
  return s;
}

// ---- pre-pass: split W (fp32) into 3 bf16 planes, packed in MFMA B-fragment
// order.  fid = et*128 + kc  (et = 16-expert tile, kc = K/32 chunk).
// wp[fid*1536 + s*512 + lane*8 ..] = W_split_s[et*16 + (lane&15)][kc*32 + (lane>>4)*8 ..]
__global__ __launch_bounds__(256) void pack_w_kernel(
    const float* __restrict__ w, ushort* __restrict__ wp)
{
  const int g    = blockIdx.x * 256 + threadIdx.x;  // 65536 threads
  const int lane = g & 63;
  const int fid  = g >> 6;                          // 0..1023
  const int et   = fid >> 7;
  const int kc   = fid & 127;
  const int e    = et * 16 + (lane & 15);
  const int k0   = kc * 32 + (lane >> 4) * 8;
  const float4 x0 = *(const float4*)(w + (size_t)e * HIDDEN + k0);
  const float4 x1 = *(const float4*)(w + (size_t)e * HIDDEN + k0 + 4);
  Split3 s = split8(x0, x1);
  uint4* dst = (uint4*)wp + (size_t)fid * 3 * 64;
  dst[0 * 64 + lane] = s.h;
  dst[1 * 64 + lane] = s.m;
  dst[2 * 64 + lane] = s.l;
}

__global__ __launch_bounds__(512, 4) void router_kernel(
    const float*  __restrict__ h,     // [T, HIDDEN]
    const ushort* __restrict__ wp,    // packed split W (see pack_w_kernel)
    const float*  __restrict__ bias,  // [NEXP]
    float* __restrict__ out,          // [T*8] indices (as float) then [T*8] weights
    int T)
{
  __shared__ float Ss[BM * SS];      // score buffer (epilogue only)
  const int tid  = threadIdx.x;
  const int row0 = blockIdx.x * BM;

  // wave roles: wn = expert-column tile (32 experts), wk = K-parity half
  const int wid  = tid >> 6;
  const int wn   = wid & 3;
  const int wk   = wid >> 2;
  const int lane = tid & 63;
  const int lrow = lane & 15;   // MFMA row/col index within 16
  const int lk   = lane >> 4;   // MFMA k-group (8 contiguous k)

  // Per-lane A-fragment global pointers: row = row0 + mi*16 + lrow,
  // k = c*64 + wk*32 + lk*8.  8 contiguous floats = 2x float4 per mi.
  const float* pA0 = h + (size_t)(row0 + lrow) * HIDDEN + wk * 32 + lk * 8;
  const float* pA1 = pA0 + (size_t)16 * HIDDEN;

  // Per-lane B fragment pointers at chunk 0; stride 3072 ushorts per chunk
  const ushort* pB0 = wp + (size_t)((wn * 2 + 0) * 128 + wk) * 1536 + (size_t)lane * 8;
  const ushort* pB1 = wp + (size_t)((wn * 2 + 1) * 128 + wk) * 1536 + (size_t)lane * 8;

  f32x4 acc[2][2];
#pragma unroll
  for (int i = 0; i < 2; ++i)
#pragma unroll
    for (int j = 0; j < 2; ++j) acc[i][j] = (f32x4){0.f, 0.f, 0.f, 0.f};

  // ---- main loop: no LDS, no barriers.  Each wave free-runs; the compiler
  // pipelines loads across iterations via counted vmcnt (unroll 2).
#pragma unroll 2
  for (int c = 0; c < NCHUNK; ++c) {
    // B fragments for this chunk (L2-resident packed W)
    short8 bf[2][3];
    const ushort* b0 = pB0 + (size_t)c * 3072;
    const ushort* b1 = pB1 + (size_t)c * 3072;
#pragma unroll
    for (int s = 0; s < 3; ++s) {
      bf[0][s] = *(const short8*)(b0 + s * 512);
      bf[1][s] = *(const short8*)(b1 + s * 512);
    }
    // A fragments: global -> registers (L1-shared across wn waves), split here
    const float4 a00 = *(const float4*)(pA0 + c * BKC);
    const float4 a01 = *(const float4*)(pA0 + c * BKC + 4);
    const float4 a10 = *(const float4*)(pA1 + c * BKC);
    const float4 a11 = *(const float4*)(pA1 + c * BKC + 4);
    short8 af[2][3];
    {
      Split3 s0 = split8(a00, a01);
      af[0][0] = *(short8*)&s0.h; af[0][1] = *(short8*)&s0.m; af[0][2] = *(short8*)&s0.l;
      Split3 s1 = split8(a10, a11);
      af[1][0] = *(short8*)&s1.h; af[1][1] = *(short8*)&s1.m; af[1][2] = *(short8*)&s1.l;
    }
    __builtin_amdgcn_s_setprio(1);
#pragma unroll
    for (int mi = 0; mi < 2; ++mi)
#pragma unroll
      for (int ni = 0; ni < 2; ++ni) {
        f32x4 cc = acc[mi][ni];
        cc = __builtin_amdgcn_mfma_f32_16x16x32_bf16(af[mi][0], bf[ni][0], cc, 0, 0, 0);
        cc = __builtin_amdgcn_mfma_f32_16x16x32_bf16(af[mi][0], bf[ni][1], cc, 0, 0, 0);
        cc = __builtin_amdgcn_mfma_f32_16x16x32_bf16(af[mi][1], bf[ni][0], cc, 0, 0, 0);
        cc = __builtin_amdgcn_mfma_f32_16x16x32_bf16(af[mi][0], bf[ni][2], cc, 0, 0, 0);
        cc = __builtin_amdgcn_mfma_f32_16x16x32_bf16(af[mi][2], bf[ni][0], cc, 0, 0, 0);
        cc = __builtin_amdgcn_mfma_f32_16x16x32_bf16(af[mi][1], bf[ni][1], cc, 0, 0, 0);
        acc[mi][ni] = cc;
      }
    __builtin_amdgcn_s_setprio(0);
  }

  // ---- combine wave-pair K-partials in LDS
  if (wk == 1) {
#pragma unroll
    for (int mi = 0; mi < 2; ++mi)
#pragma unroll
      for (int ni = 0; ni < 2; ++ni)
#pragma unroll
        for (int j = 0; j < 4; ++j)
          // D layout (m89): col = lane&15, row = (lane>>4)*4 + j
          Ss[(mi * 16 + lk * 4 + j) * SS + wn * 32 + ni * 16 + lrow] = acc[mi][ni][j];
  }
  __syncthreads();
  if (wk == 0) {
#pragma unroll
    for (int mi = 0; mi < 2; ++mi)
#pragma unroll
      for (int ni = 0; ni < 2; ++ni)
#pragma unroll
        for (int j = 0; j < 4; ++j) {
          const int ixs = (mi * 16 + lk * 4 + j) * SS + wn * 32 + ni * 16 + lrow;
          Ss[ixs] += acc[mi][ni][j];
        }
  }
  __syncthreads();

  // ---- top-k epilogue: wave wid handles tokens wid, wid+8, ...
  const float bb0 = bias[lane];
  const float bb1 = bias[lane + 64];

  for (int t = wid; t < BM; t += 8) {
    const float lg0 = Ss[t * SS + lane];
    const float lg1 = Ss[t * SS + 64 + lane];
    const float s0 = 1.0f / (1.0f + expf(-lg0));  // raw sigmoid score
    const float s1 = 1.0f / (1.0f + expf(-lg1));
    float c0 = s0 + bb0;                          // bias-corrected, for selection
    float c1 = s1 + bb1;

    int   sel_i[TOPK];
    float sel_r[TOPK];
    float rsum = 0.0f;
#pragma unroll
    for (int j = 0; j < TOPK; ++j) {
      const bool take0 = (c0 >= c1);
      float v  = take0 ? c0 : c1;
      float rr = take0 ? s0 : s1;
      int   ii = take0 ? lane : lane + 64;
#pragma unroll
      for (int off = 32; off > 0; off >>= 1) {
        const float ov  = __shfl_xor(v, off, 64);
        const float orr = __shfl_xor(rr, off, 64);
        const int   oi  = __shfl_xor(ii, off, 64);
        if (ov > v || (ov == v && oi < ii)) { v = ov; rr = orr; ii = oi; }
      }
      sel_i[j] = ii;
      sel_r[j] = rr;
      rsum += rr;
      if (ii == lane)      c0 = -__builtin_inff();
      if (ii == lane + 64) c1 = -__builtin_inff();
    }
    if (lane == 0) {
      const float inv = 1.0f / (rsum + 1e-20f);
      const size_t tok = (size_t)(row0 + t);
#pragma unroll
      for (int j = 0; j < TOPK; ++j) {
        out[tok * TOPK + j]                    = (float)sel_i[j];
        out[(size_t)T * TOPK + tok * TOPK + j] = sel_r[j] * inv;
      }
    }
  }
}

extern "C" void kernel_launch(void* const* d_in, const int* in_sizes, int n_in,
                              void* d_out, int out_size, void* d_ws, size_t ws_size,
                              hipStream_t stream) {
  const float* h    = (const float*)d_in[0];
  const float* w    = (const float*)d_in[1];
  const float* bias = (const float*)d_in[2];
  float* out = (float*)d_out;
  ushort* wp = (ushort*)d_ws;          // needs 1024*1536*2 B = 3 MiB
  const int T = in_sizes[0] / HIDDEN;  // 16384

  hipLaunchKernelGGL(pack_w_kernel, dim3(256), dim3(256), 0, stream, w, wp);

  dim3 grid(T / BM);   // 512 blocks -> 2 per CU
  dim3 block(512);     // 8 waves: 4 expert tiles x 2 K-halves
  hipLaunchKernelGGL(router_kernel, grid, block, 0, stream, h, wp, bias, out, T);
}